// Round 2
// baseline (416.332 us; speedup 1.0000x reference)
//
#include <hip/hip_runtime.h>
#include <hip/hip_bf16.h>
#include <math.h>

typedef __attribute__((ext_vector_type(4))) float f32x4;
typedef __attribute__((ext_vector_type(16))) float f32x16;
typedef __attribute__((ext_vector_type(8))) int i32x8;
typedef __attribute__((ext_vector_type(4))) int i32x4;

#define BM 256
#define BN 256
#define BK 128
#define TEMP_INV 14.2857142857142857f   // 1/0.07
#define UNIT_SCALE 0x7f7f7f7f           // E8M0 127 -> x1.0 exact (verified)

union frag32 {
  i32x8 v8;
  struct { i32x4 lo; i32x4 hi; } s;
};

// ---- async global->LDS, 16B per lane
static __device__ inline void async16(const void* g, void* l) {
  __builtin_amdgcn_global_load_lds(
      (const __attribute__((address_space(1))) unsigned int*)g,
      (__attribute__((address_space(3))) unsigned int*)l,
      16, 0, 0);
}

// ============================================================
// Kernel 1: L2-normalize rows of A and B (D=1024), emit fp8 e4m3
// (plain row-major). Also zeroes pos/neg accumulators. (unchanged)
// ============================================================
__global__ __launch_bounds__(256) void normalize_rows(
    const float* __restrict__ a, const float* __restrict__ b,
    unsigned char* __restrict__ oa, unsigned char* __restrict__ ob,
    float* __restrict__ pos_acc, float* __restrict__ neg_acc,
    int N, int D) {
  const int blk = blockIdx.x;
  const float* in;
  unsigned char* out;
  if (blk < N) {
    in = a + (size_t)blk * D;
    out = oa + (size_t)blk * D;
    if (threadIdx.x == 0) { pos_acc[blk] = 0.f; neg_acc[blk] = 0.f; }
  } else {
    in = b + (size_t)(blk - N) * D;
    out = ob + (size_t)(blk - N) * D;
  }
  const int t = threadIdx.x;
  const float4 v = ((const float4*)in)[t];
  float ss = v.x * v.x + v.y * v.y + v.z * v.z + v.w * v.w;
#pragma unroll
  for (int m = 32; m >= 1; m >>= 1) ss += __shfl_xor(ss, m, 64);
  __shared__ float wsum[4];
  const int wave = t >> 6, lane = t & 63;
  if (lane == 0) wsum[wave] = ss;
  __syncthreads();
  const float tot = wsum[0] + wsum[1] + wsum[2] + wsum[3];
  const float inv = 1.0f / fmaxf(sqrtf(tot), 1e-12f);
  int r = __builtin_amdgcn_cvt_pk_fp8_f32(v.x * inv, v.y * inv, 0, false);
  r = __builtin_amdgcn_cvt_pk_fp8_f32(v.z * inv, v.w * inv, r, true);
  ((int*)out)[t] = r;
}

// ============================================================
// Kernel 2: fused MX-fp8 MFMA GEMM + exp epilogue.
// R2: attack the operand-byte economy (R1 showed schedule is not the
// bottleneck; LDS feed + 4-way b128 conflicts are).
//  * mfma_scale_f32_32x32x64_f8f6f4: 2x FLOP per LDS operand byte.
//  * Slot-major (column-major over 16B chunks) LDS layout:
//    chunk(s,row) = s*256+row, addr = chunk*16. global_load_lds writes
//    linearly (chunk = u*512+tid); the per-lane GLOBAL source provides
//    the permutation (s = 2u+(tid>>8), row = tid&255). Fragment
//    ds_read_b128 then covers 32 consecutive 16B chunks -> all 32
//    banks -> ZERO conflicts.
//  * Frag layout (mirrors verified 16x16x128): A row=lane&31,
//    k=(lane>>5)*32+e; B col=lane&31 same k. C/D 32x32 (verified):
//    col=lane&31, row=(reg&3)+8*(reg>>2)+4*(lane>>5).
//  * B frags (4) held in regs whole tile; A frags rolling (cur+next)
//    with counted lgkmcnt(4) + sched_barrier fences (rule #18).
//  * One __syncthreads per K-tile; staging issued a full tile ahead.
// Wave = 128x64 output = 4mi x 2nj of 32x32 tiles; acc = 128 VGPR.
// ============================================================
__global__ __launch_bounds__(512, 2) void infonce_gemm(
    const unsigned char* __restrict__ A, const unsigned char* __restrict__ B,
    const int* __restrict__ la, const int* __restrict__ lb,
    float* __restrict__ pos_acc, float* __restrict__ neg_acc, int D) {
  __shared__ __align__(16) unsigned char sA[2][BM * BK];  // 2 x 32 KB
  __shared__ __align__(16) unsigned char sB[2][BN * BK];  // 2 x 32 KB

  const int tid = threadIdx.x;
  const int lane = tid & 63;
  const int wave = tid >> 6;  // 0..7
  const int wm = wave >> 2;   // 0..1  (M half: 128 rows)
  const int wn = wave & 3;    // 0..3  (N quarter: 64 cols)
  const int row0 = blockIdx.y * BM;
  const int col0 = blockIdx.x * BN;

  // staging: thread tid covers chunk u*512+tid = (s=2u+(tid>>8), row=tid&255)
  const int srow = tid & 255;
  const int sseg = tid >> 8;
  const unsigned char* gA = A + (size_t)(row0 + srow) * 1024 + sseg * 16;
  const unsigned char* gB = B + (size_t)(col0 + srow) * 1024 + sseg * 16;

  const int l31 = lane & 31;
  const int hi = lane >> 5;
  const int lane16 = l31 * 16 + hi * 8192;  // row chunk + k-half slot pair

  const int offA = wm * 2048 + lane16;  // + mi*512 + ks*16384 (+4096 hi slot)
  const int offB = wn * 1024 + lane16;  // + nj*512 + ks*16384

  f32x16 acc[4][2] = {};

#define STAGE8(bf, kt)                                              \
  do {                                                              \
    _Pragma("unroll") for (int u = 0; u < 4; u++) {                 \
      async16(gA + (size_t)(kt) * 128 + u * 32,                     \
              &sA[bf][u * 8192 + tid * 16]);                        \
      async16(gB + (size_t)(kt) * 128 + u * 32,                     \
              &sB[bf][u * 8192 + tid * 16]);                        \
    }                                                               \
  } while (0)

// 32B fragment: two b128 from consecutive slot planes (conflict-free)
#define LD32(dst, base, off)                                        \
  do {                                                              \
    frag32 _f;                                                      \
    _f.s.lo = *(const i32x4*)((base) + (off));                      \
    _f.s.hi = *(const i32x4*)((base) + (off) + 4096);               \
    dst = _f.v8;                                                    \
  } while (0)

#define MFMA(ci, a, b)                                              \
  ci = __builtin_amdgcn_mfma_scale_f32_32x32x64_f8f6f4(             \
      a, b, ci, 0, 0, 0, UNIT_SCALE, 0, UNIT_SCALE)

  STAGE8(0, 0);
  __syncthreads();  // full drain: tile 0 resident

#pragma unroll 1
  for (int t = 0; t < 8; ++t) {
    const int h = t & 1;
    const unsigned char* cA = sA[h];
    const unsigned char* cB = sB[h];

    i32x8 b00, b10, b01, b11, ac0, ac1, an0, an1;
    // group 0: all 4 B frags + A(mi=0) both k-steps  (12 ds_read_b128)
    LD32(b00, cB, offB);                 // nj0 ks0
    LD32(b10, cB, offB + 512);           // nj1 ks0
    LD32(b01, cB, offB + 16384);         // nj0 ks1
    LD32(b11, cB, offB + 16384 + 512);   // nj1 ks1
    LD32(ac0, cA, offA);                 // mi0 ks0
    LD32(ac1, cA, offA + 16384);         // mi0 ks1
    if (t < 7) STAGE8(h ^ 1, t + 1);     // prefetch next tile (vmcnt only)
    __builtin_amdgcn_sched_barrier(0);   // pin group 0 before group 1

#define MI_STEP(mi)                                                 \
    do {                                                            \
      if ((mi) < 3) {                                               \
        LD32(an0, cA, offA + ((mi) + 1) * 512);                     \
        LD32(an1, cA, offA + 16384 + ((mi) + 1) * 512);             \
        asm volatile("s_waitcnt lgkmcnt(4)" ::: "memory");          \
      } else {                                                      \
        asm volatile("s_waitcnt lgkmcnt(0)" ::: "memory");          \
      }                                                             \
      __builtin_amdgcn_sched_barrier(0);                            \
      __builtin_amdgcn_s_setprio(1);                                \
      MFMA(acc[mi][0], ac0, b00);                                   \
      MFMA(acc[mi][1], ac0, b10);                                   \
      MFMA(acc[mi][0], ac1, b01);                                   \
      MFMA(acc[mi][1], ac1, b11);                                   \
      __builtin_amdgcn_s_setprio(0);                                \
      __builtin_amdgcn_sched_barrier(0);                            \
      if ((mi) < 3) { ac0 = an0; ac1 = an1; }                       \
    } while (0)

    MI_STEP(0);
    MI_STEP(1);
    MI_STEP(2);
    MI_STEP(3);
#undef MI_STEP

    __syncthreads();  // reads done + next tile's staging drained
  }

  // ---- epilogue: 32x32 C/D layout col=lane&31,
  //      row=(reg&3)+8*(reg>>2)+4*(lane>>5)  (guide m74/m101, verified)
  const int lb0 = lb[col0 + wn * 64 + l31];
  const int lb1 = lb[col0 + wn * 64 + 32 + l31];
  const int rbase = row0 + wm * 128 + 4 * hi;

#pragma unroll
  for (int mi = 0; mi < 4; mi++) {
#pragma unroll
    for (int r = 0; r < 16; r++) {
      const int row = rbase + mi * 32 + (r & 3) + 8 * (r >> 2);
      const int lav = la[row];
      float s0 = acc[mi][0][r] * TEMP_INV;
      float s1 = acc[mi][1][r] * TEMP_INV;
      s0 = fminf(fmaxf(s0, -50.f), 50.f);
      s1 = fminf(fmaxf(s1, -50.f), 50.f);
      const float e0 = __expf(s0);
      const float e1 = __expf(s1);
      float sneg = e0 + e1;
      float spos = (lav == lb0 ? e0 : 0.f) + (lav == lb1 ? e1 : 0.f);
#pragma unroll
      for (int m = 16; m >= 1; m >>= 1) {
        sneg += __shfl_xor(sneg, m, 32);
        spos += __shfl_xor(spos, m, 32);
      }
      if (l31 == 0) {
        atomicAdd(&neg_acc[row], sneg);
        atomicAdd(&pos_acc[row], spos);
      }
    }
  }
}

// ============================================================
// Kernel 3: loss = mean( log(neg) - log(max(pos,1e-8)) ) (unchanged)
// ============================================================
__global__ __launch_bounds__(1024) void final_reduce(
    const float* __restrict__ pos, const float* __restrict__ neg,
    float* __restrict__ out, int N) {
  double local = 0.0;
  const int t = threadIdx.x;
  for (int i = t; i < N / 4; i += 1024) {
    const float4 p4 = ((const float4*)pos)[i];
    const float4 n4 = ((const float4*)neg)[i];
    local += (double)(logf(n4.x) - logf(fmaxf(p4.x, 1e-8f)));
    local += (double)(logf(n4.y) - logf(fmaxf(p4.y, 1e-8f)));
    local += (double)(logf(n4.z) - logf(fmaxf(p4.z, 1e-8f)));
    local += (double)(logf(n4.w) - logf(fmaxf(p4.w, 1e-8f)));
  }
#pragma unroll
  for (int m = 32; m >= 1; m >>= 1) local += __shfl_xor(local, m, 64);
  __shared__ double wsum[16];
  const int wave = t >> 6, lane = t & 63;
  if (lane == 0) wsum[wave] = local;
  __syncthreads();
  if (t == 0) {
    double tot = 0.0;
#pragma unroll
    for (int w = 0; w < 16; w++) tot += wsum[w];
    out[0] = (float)(tot / (double)N);
  }
}

extern "C" void kernel_launch(void* const* d_in, const int* in_sizes, int n_in,
                              void* d_out, int out_size, void* d_ws, size_t ws_size,
                              hipStream_t stream) {
  const float* fa = (const float*)d_in[0];
  const float* fb = (const float*)d_in[1];
  const int* la = (const int*)d_in[2];
  const int* lb = (const int*)d_in[3];

  const int D = 1024;
  const int N = in_sizes[0] / D;  // 8192
  const int M = in_sizes[1] / D;  // 8192

  unsigned char* nA = (unsigned char*)d_ws;
  unsigned char* nB = nA + (size_t)N * D;
  float* pos = (float*)(nB + (size_t)M * D);
  float* neg = pos + N;

  normalize_rows<<<N + M, 256, 0, stream>>>(fa, fb, nA, nB, pos, neg, N, D);

  dim3 grid(M / BN, N / BM);
  infonce_gemm<<<grid, 512, 0, stream>>>(nA, nB, la, lb, pos, neg, D);

  final_reduce<<<1, 1024, 0, stream>>>(pos, neg, (float*)d_out, N);
}